// Round 7
// baseline (207.280 us; speedup 1.0000x reference)
//
#include <hip/hip_runtime.h>
#include <math.h>

// ConvCaps EM routing, fp32 I/O. R7: TWO positions per block -> 196 blocks
// (<=256 CUs: no second dispatch layer, fixes the 392-block imbalance where
// 136 CUs ran 2 blocks serially). W-tile loaded once per k-iter, reused for
// both positions (halves L2 load pressure per work); two independent softmax
// shuffle chains give ~2x ILP at 2 waves/SIMD. Stats via LDS float atomicAdd
// moment buffer (ds_add_f32, 4.2 KB) used sequentially per position.
// 512 threads (R5/R6-proven phase discipline). launch_bounds(512,2): 256-VGPR
// budget (R3: tighter bounds spilled; watch WRITE_SIZE).

#define NTH 512
#define KK 288
#define KT 18         // 288 / 16 k-groups
#define CC 32
#define PS 16
#define EPSF 1e-8f
#define LAMF 1e-3f
#define HL2PI 0.91893853320467274178f   // 0.5*ln(2*pi)

__device__ __forceinline__ float4 ld4(const float* p){ return *(const float4*)p; }
__device__ __forceinline__ float rcpf(float x){ return __builtin_amdgcn_rcpf(x); }

extern "C" __global__ void __launch_bounds__(NTH, 2)
convcaps_em_kernel(const float* __restrict__ x, const float* __restrict__ wgt,
                   const float* __restrict__ beta_a, const float* __restrict__ beta_u,
                   float* __restrict__ out)
{
  __shared__ float sP[2*KK*PS];     // poses x2, xor-swizzled (36864 B)
  __shared__ float sA[2*KK];        // f = a/(a+eps) x2 (2304 B)
  __shared__ float sPF[CC*33];      // atomic moment buffer t0|t1[16]|t2[16] (4224 B)
  __shared__ float sMu[2*CC*17];    // (4352 B)
  __shared__ float sNI2[2*CC*17];   // -0.5/sigma^2 (4352 B)
  __shared__ float sLc[2*CC];       // ln(a_out) - lsum - 16*HL2PI (256 B)
  __shared__ float sAo[2*CC];       // (256 B)
  // total 52608 B

  const int tid = threadIdx.x;
  const int n0  = blockIdx.x*2, n1 = n0 + 1;

  const int c  = tid & 31;    // sweep layout: c in 32-lane half (softmax over c)
  const int ks = tid >> 5;    // k-group 0..15
  const int w  = tid >> 6;    // wave 0..7
  const int cc = tid >> 4;    // stats layout: one thread per (cc, pp)
  const int pp = tid & 15;

  // ---- stage both positions' poses (xor-swizzled) + activations ----
  for (int q = 0; q < 2; ++q) {
    const int n = n0 + q;
    const int b = n/49, r49 = n - b*49, ohi = r49/7, owi = r49 - ohi*7;
    const float* xw = x + ((size_t)b*16 + (size_t)(ohi*2))*16*544 + (size_t)(owi*2)*544;
    for (int idx = tid; idx < KK*PS/4; idx += NTH) {   // 1152 float4s
      const int sp = idx >> 7, ch4 = idx & 127;
      const int kh = sp/3, kw = sp - kh*3;
      const float4 v = ld4(&xw[kh*(16*544) + kw*544 + ch4*4]);
      const int k = sp*32 + (ch4 >> 2), g = ch4 & 3;
      *(float4*)&sP[q*(KK*PS) + (k<<4) + ((g ^ ((k>>1)&3))<<2)] = v;
    }
    if (tid < KK/4) {
      const int sp = tid >> 3, bc4 = tid & 7;
      const int kh = sp/3, kw = sp - kh*3;
      const float4 v = ld4(&xw[kh*(16*544) + kw*544 + 512 + bc4*4]);
      *(float4*)&sA[q*KK + sp*32 + bc4*4] = v;
    }
  }
  __syncthreads();
  if (tid < KK) {
    const float a0 = sA[tid];      sA[tid]      = a0 * rcpf(a0 + EPSF);
    const float a1 = sA[KK + tid]; sA[KK + tid] = a1 * rcpf(a1 + EPSF);
  }
  __syncthreads();

  float t0[2], t1[2][PS], t2[2][PS];

  // ---- stats for one position via LDS atomic moment buffer ----
  auto stats = [&](int q){
    float u0 = t0[q];
    u0 += __shfl_xor(u0, 32);
    float u1[PS], u2[PS];
#pragma unroll
    for (int p = 0; p < PS; ++p) {
      u1[p] = t1[q][p] + __shfl_xor(t1[q][p], 32);
      u2[p] = t2[q][p] + __shfl_xor(t2[q][p], 32);
    }
    const bool lead = (tid & 32) == 0;
    if (lead && w == 0) {           // wave 0 stores (no zeroing pass needed)
      float* pr = &sPF[c*33];
      pr[0] = u0;
#pragma unroll
      for (int p = 0; p < PS; ++p) { pr[1+p] = u1[p]; pr[17+p] = u2[p]; }
    }
    __syncthreads();
    if (lead && w != 0) {           // waves 1..7 accumulate
      float* pr = &sPF[c*33];
      atomicAdd(&pr[0], u0);
#pragma unroll
      for (int p = 0; p < PS; ++p) {
        atomicAdd(&pr[1+p],  u1[p]);
        atomicAdd(&pr[17+p], u2[p]);
      }
    }
    __syncthreads();
    {
      const float T0 = sPF[cc*33];
      const float T1 = sPF[cc*33 + 1 + pp];
      const float T2 = sPF[cc*33 + 17 + pp];
      const float z   = rcpf(T0 + EPSF);
      const float mu  = T1 * z;
      const float s0  = T0 * z;
      const float var = fmaxf(T2*z - mu*mu*(2.f - s0), 0.f) + EPSF;
      sMu[q*(CC*17) + cc*17 + pp]  = mu;
      sNI2[q*(CC*17) + cc*17 + pp] = -0.5f * rcpf(var);
      float lsum = 0.5f * __logf(var);
      lsum += __shfl_xor(lsum, 1);  lsum += __shfl_xor(lsum, 2);
      lsum += __shfl_xor(lsum, 4);  lsum += __shfl_xor(lsum, 8);
      if (pp == 0) {
        const float cost = (16.f*beta_u[cc] + lsum) * T0;   // r_sum = T0
        const float ao = rcpf(1.f + __expf(-(LAMF*(beta_a[cc] - cost))));
        sAo[q*CC + cc] = ao;
        sLc[q*CC + cc] = __logf(ao) - lsum - 16.f*HL2PI;
      }
    }
    __syncthreads();
  };

  // ---- sweep 0: r uniform -> rr = f/32 ----
#pragma unroll
  for (int q = 0; q < 2; ++q) {
    t0[q] = 0.f;
#pragma unroll
    for (int p = 0; p < PS; ++p) { t1[q][p] = 0.f; t2[q][p] = 0.f; }
  }
  for (int kt = 0; kt < KT; ++kt) {
    const int k = kt*16 + ks;
    const float4* wg = (const float4*)(wgt + (((size_t)(k*32 + c)) << 4));
    const float4 w0 = wg[0], w1 = wg[1], w2 = wg[2], w3 = wg[3];
    const int sw = (k>>1)&3;
#pragma unroll
    for (int q = 0; q < 2; ++q) {
      const float* pb = &sP[q*(KK*PS) + (k<<4)];
      const float4 Pi[4] = { ld4(pb + ((0^sw)<<2)), ld4(pb + ((1^sw)<<2)),
                             ld4(pb + ((2^sw)<<2)), ld4(pb + ((3^sw)<<2)) };
      const float rr = sA[q*KK + k] * (1.0f/32.0f);
      t0[q] += rr;
#pragma unroll
      for (int i = 0; i < 4; ++i) {
        float v0 = Pi[i].x*w0.x; v0 = fmaf(Pi[i].y, w1.x, v0); v0 = fmaf(Pi[i].z, w2.x, v0); v0 = fmaf(Pi[i].w, w3.x, v0);
        float v1 = Pi[i].x*w0.y; v1 = fmaf(Pi[i].y, w1.y, v1); v1 = fmaf(Pi[i].z, w2.y, v1); v1 = fmaf(Pi[i].w, w3.y, v1);
        float v2 = Pi[i].x*w0.z; v2 = fmaf(Pi[i].y, w1.z, v2); v2 = fmaf(Pi[i].z, w2.z, v2); v2 = fmaf(Pi[i].w, w3.z, v2);
        float v3 = Pi[i].x*w0.w; v3 = fmaf(Pi[i].y, w1.w, v3); v3 = fmaf(Pi[i].z, w2.w, v3); v3 = fmaf(Pi[i].w, w3.w, v3);
        const float m0 = rr*v0, m1 = rr*v1, m2 = rr*v2, m3 = rr*v3;
        t1[q][i*4+0] += m0; t2[q][i*4+0] = fmaf(m0, v0, t2[q][i*4+0]);
        t1[q][i*4+1] += m1; t2[q][i*4+1] = fmaf(m1, v1, t2[q][i*4+1]);
        t1[q][i*4+2] += m2; t2[q][i*4+2] = fmaf(m2, v2, t2[q][i*4+2]);
        t1[q][i*4+3] += m3; t2[q][i*4+3] = fmaf(m3, v3, t2[q][i*4+3]);
      }
    }
  }
  stats(0);
  stats(1);

  // ---- sweeps 1,2: ln_p(prev stats) -> softmax over c -> rr -> moments ----
  for (int it = 1; it < 3; ++it) {
    float mu[2][PS], ni2[2][PS], lc[2];
#pragma unroll
    for (int q = 0; q < 2; ++q) {
#pragma unroll
      for (int p = 0; p < PS; ++p) {
        mu[q][p]  = sMu[q*(CC*17) + c*17 + p];
        ni2[q][p] = sNI2[q*(CC*17) + c*17 + p];
      }
      lc[q] = sLc[q*CC + c];
      t0[q] = 0.f;
#pragma unroll
      for (int p = 0; p < PS; ++p) { t1[q][p] = 0.f; t2[q][p] = 0.f; }
    }
    for (int kt = 0; kt < KT; ++kt) {
      const int k = kt*16 + ks;
      const float4* wg = (const float4*)(wgt + (((size_t)(k*32 + c)) << 4));
      const float4 w0 = wg[0], w1 = wg[1], w2 = wg[2], w3 = wg[3];
      const int sw = (k>>1)&3;
#pragma unroll
      for (int q = 0; q < 2; ++q) {
        const float* pb = &sP[q*(KK*PS) + (k<<4)];
        const float4 Pi[4] = { ld4(pb + ((0^sw)<<2)), ld4(pb + ((1^sw)<<2)),
                               ld4(pb + ((2^sw)<<2)), ld4(pb + ((3^sw)<<2)) };
        float v[PS];
#pragma unroll
        for (int i = 0; i < 4; ++i) {
          float v0 = Pi[i].x*w0.x; v0 = fmaf(Pi[i].y, w1.x, v0); v0 = fmaf(Pi[i].z, w2.x, v0); v0 = fmaf(Pi[i].w, w3.x, v0);
          float v1 = Pi[i].x*w0.y; v1 = fmaf(Pi[i].y, w1.y, v1); v1 = fmaf(Pi[i].z, w2.y, v1); v1 = fmaf(Pi[i].w, w3.y, v1);
          float v2 = Pi[i].x*w0.z; v2 = fmaf(Pi[i].y, w1.z, v2); v2 = fmaf(Pi[i].z, w2.z, v2); v2 = fmaf(Pi[i].w, w3.z, v2);
          float v3 = Pi[i].x*w0.w; v3 = fmaf(Pi[i].y, w1.w, v3); v3 = fmaf(Pi[i].z, w2.w, v3); v3 = fmaf(Pi[i].w, w3.w, v3);
          v[i*4+0] = v0; v[i*4+1] = v1; v[i*4+2] = v2; v[i*4+3] = v3;
        }
        float acc = 0.f;
#pragma unroll
        for (int p = 0; p < PS; ++p) {
          const float d = v[p] - mu[q][p];
          acc = fmaf(d*d, ni2[q][p], acc);
        }
        const float lnap = acc + lc[q];
        float m = lnap;        // softmax over c within each 32-lane half
        m = fmaxf(m, __shfl_xor(m, 1));  m = fmaxf(m, __shfl_xor(m, 2));
        m = fmaxf(m, __shfl_xor(m, 4));  m = fmaxf(m, __shfl_xor(m, 8));
        m = fmaxf(m, __shfl_xor(m, 16));
        const float e = __expf(lnap - m);
        float s = e;
        s += __shfl_xor(s, 1);  s += __shfl_xor(s, 2);  s += __shfl_xor(s, 4);
        s += __shfl_xor(s, 8);  s += __shfl_xor(s, 16);
        const float rr = e * rcpf(s) * sA[q*KK + k];   // r * a/(a+eps)
        t0[q] += rr;
#pragma unroll
        for (int p = 0; p < PS; ++p) {
          const float tmp = rr * v[p];
          t1[q][p] += tmp;
          t2[q][p] = fmaf(tmp, v[p], t2[q][p]);
        }
      }
    }
    stats(0);
    stats(1);
  }

  // ---- epilogue: both positions ----
  out[(size_t)n0*544 + tid] = sMu[(tid>>4)*17 + (tid&15)];
  out[(size_t)n1*544 + tid] = sMu[CC*17 + (tid>>4)*17 + (tid&15)];
  if (tid < CC) {
    out[(size_t)n0*544 + 512 + tid] = sAo[tid];
    out[(size_t)n1*544 + 512 + tid] = sAo[CC + tid];
  }
}

extern "C" void kernel_launch(void* const* d_in, const int* in_sizes, int n_in,
                              void* d_out, int out_size, void* d_ws, size_t ws_size,
                              hipStream_t stream) {
  (void)in_sizes; (void)n_in; (void)d_ws; (void)ws_size; (void)out_size;
  const float* x  = (const float*)d_in[0];
  const float* w  = (const float*)d_in[1];
  const float* ba = (const float*)d_in[2];
  const float* bu = (const float*)d_in[3];
  float* out = (float*)d_out;
  convcaps_em_kernel<<<dim3(196), dim3(NTH), 0, stream>>>(x, w, ba, bu, out);
}